// Round 20
// baseline (148.666 us; speedup 1.0000x reference)
//
#include <hip/hip_runtime.h>
#include <hip/hip_bf16.h>
#include <hip/hip_fp16.h>

#define C 64
#define GRP 64         // edge groups; tag bits 26..31 (g<64), rank in bits 0..25
#define RMASK 0x03FFFFFFu

__device__ __forceinline__ __half2 u2h(unsigned u) {
    __half2 h; *(unsigned*)&h = u; return h;
}
__device__ __forceinline__ unsigned h2u(__half2 h) {
    return *(unsigned*)&h;
}

// ---- K1: LDS-histogram count ----
// part is NODE-MAJOR [node][GRP]: count dumps scattered 4B stores (latency-
// hidable; count has spare store capacity), so that scan phase A can stream
// each node's 64 partials as 16 contiguous uint4 (R19's group-major layout
// made phase A walk 64 strided locations at 1.5 TB/s -> 28us of 43us).
__global__ void __launch_bounds__(256)
count_range_kernel(const int* __restrict__ dst, unsigned* __restrict__ part, int R,
                   int RNG, unsigned* __restrict__ rank, unsigned* __restrict__ gctr,
                   int Ec, int E) {
    __shared__ unsigned hist[6400];        // supports R <= 6400
    int t = threadIdx.x;
    int g = blockIdx.x / RNG;
    int r = blockIdx.x - g * RNG;
    unsigned rbase = (unsigned)r * (unsigned)R;
    for (int i = t; i < R; i += 256) hist[i] = 0u;
    if (blockIdx.x == 0 && t == 0) *gctr = 0u;   // consumed by next kernel
    __syncthreads();

    int e0 = g * Ec;                       // Ec is a multiple of 4; e0 16B-aligned
    int e1 = min(E, e0 + Ec);
    int nv = (e1 - e0) >> 2;
    const uint4* dv = (const uint4*)(dst + e0);
    unsigned gtag = (unsigned)g << 26;
    for (int i = t; i < nv; i += 256) {
        uint4 d4 = dv[i];
        int eb = e0 + i * 4;
        unsigned o0 = d4.x - rbase, o1 = d4.y - rbase, o2 = d4.z - rbase, o3 = d4.w - rbase;
        if (o0 < (unsigned)R) rank[eb + 0] = gtag | atomicAdd(&hist[o0], 1u);
        if (o1 < (unsigned)R) rank[eb + 1] = gtag | atomicAdd(&hist[o1], 1u);
        if (o2 < (unsigned)R) rank[eb + 2] = gtag | atomicAdd(&hist[o2], 1u);
        if (o3 < (unsigned)R) rank[eb + 3] = gtag | atomicAdd(&hist[o3], 1u);
    }
    for (int e = e0 + nv * 4 + t; e < e1; e += 256) {   // scalar tail
        unsigned o = (unsigned)dst[e] - rbase;
        if (o < (unsigned)R) rank[e] = gtag | atomicAdd(&hist[o], 1u);
    }
    __syncthreads();
    // node-major dump: part[(rbase+i)*GRP + g]
    for (int i = t; i < R; i += 256) {
        part[(size_t)(rbase + i) * GRP + g] = hist[i];
    }
}

// ---- K2: fused per-chunk scan + gemm (chunk = 256 nodes, 4 tiles of 64 rows) ----
// Phase A streams each node's 64 partials contiguously (16 uint4 in, 16 out).
__global__ void __launch_bounds__(256, 4)
scan_gemm_kernel(unsigned* __restrict__ part,
                 const float* __restrict__ x, const float* __restrict__ W,
                 unsigned* __restrict__ deg, unsigned* __restrict__ offs,
                 unsigned* __restrict__ gctr, float* __restrict__ dis,
                 unsigned short* __restrict__ hsb, int N) {
    __shared__ float Wl[64][64];
    __shared__ float Xl[64][68];
    __shared__ unsigned s[256];
    __shared__ float sdis[256];
    __shared__ unsigned sbase;
    int t = threadIdx.x;
    int nbase = blockIdx.x * 256;

    for (int i = t; i < 1024; i += 256) {
        ((float4*)Wl)[i] = ((const float4*)W)[i];
    }

    // --- phase A: one node per thread; contiguous 256B in/out per node ---
    int i = nbase + t;
    unsigned degv = 0;
    if (i < N) {
        unsigned run = 0;
        uint4* p = (uint4*)&part[(size_t)i * GRP];
        #pragma unroll
        for (int q = 0; q < GRP / 4; ++q) {
            uint4 v = p[q];
            uint4 w;
            w.x = run;
            w.y = run + v.x;
            w.z = run + v.x + v.y;
            w.w = run + v.x + v.y + v.z;
            p[q] = w;                     // exclusive prefix across groups
            run += v.x + v.y + v.z + v.w;
        }
        degv = run;
        deg[i] = run;
        float dv = rsqrtf((float)(run + 1u));
        dis[i] = dv;
        sdis[t] = dv;
    } else {
        sdis[t] = 0.f;
    }
    s[t] = degv;
    __syncthreads();
    for (int d = 1; d < 256; d <<= 1) {
        unsigned v = (t >= d) ? s[t - d] : 0u;
        __syncthreads();
        s[t] += v;
        __syncthreads();
    }
    if (t == 255) sbase = atomicAdd(gctr, s[255]);   // global chunk base
    __syncthreads();
    if (i < N) offs[i] = sbase + s[t] - degv;        // global exclusive offset
    __syncthreads();

    // --- phase B: 4 gemm tiles of 64 rows ---
    int tx = t & 15;      // channel group
    int ty = t >> 4;      // row group
    for (int tile = 0; tile < 4; ++tile) {
        int rbase = nbase + tile * 64;
        if (rbase >= N) break;            // block-uniform
        for (int ii = t; ii < 1024; ii += 256) {
            int r = ii >> 4, kq = ii & 15;
            float4 v;
            if (rbase + r < N) v = ((const float4*)(x + (size_t)(rbase + r) * C))[kq];
            else               v = make_float4(0.f, 0.f, 0.f, 0.f);
            *(float4*)&Xl[r][kq * 4] = v;
        }
        __syncthreads();
        float4 acc[4];
        #pragma unroll
        for (int j = 0; j < 4; ++j) acc[j] = make_float4(0.f, 0.f, 0.f, 0.f);
        #pragma unroll 2
        for (int kb = 0; kb < 16; ++kb) {
            float4 wv0 = *(const float4*)&Wl[kb * 4 + 0][tx * 4];
            float4 wv1 = *(const float4*)&Wl[kb * 4 + 1][tx * 4];
            float4 wv2 = *(const float4*)&Wl[kb * 4 + 2][tx * 4];
            float4 wv3 = *(const float4*)&Wl[kb * 4 + 3][tx * 4];
            #pragma unroll
            for (int j = 0; j < 4; ++j) {
                float4 xv = *(const float4*)&Xl[ty * 4 + j][kb * 4];
                acc[j].x = fmaf(xv.x, wv0.x, acc[j].x);
                acc[j].y = fmaf(xv.x, wv0.y, acc[j].y);
                acc[j].z = fmaf(xv.x, wv0.z, acc[j].z);
                acc[j].w = fmaf(xv.x, wv0.w, acc[j].w);
                acc[j].x = fmaf(xv.y, wv1.x, acc[j].x);
                acc[j].y = fmaf(xv.y, wv1.y, acc[j].y);
                acc[j].z = fmaf(xv.y, wv1.z, acc[j].z);
                acc[j].w = fmaf(xv.y, wv1.w, acc[j].w);
                acc[j].x = fmaf(xv.z, wv2.x, acc[j].x);
                acc[j].y = fmaf(xv.z, wv2.y, acc[j].y);
                acc[j].z = fmaf(xv.z, wv2.z, acc[j].z);
                acc[j].w = fmaf(xv.z, wv2.w, acc[j].w);
                acc[j].x = fmaf(xv.w, wv3.x, acc[j].x);
                acc[j].y = fmaf(xv.w, wv3.y, acc[j].y);
                acc[j].z = fmaf(xv.w, wv3.z, acc[j].z);
                acc[j].w = fmaf(xv.w, wv3.w, acc[j].w);
            }
        }
        #pragma unroll
        for (int j = 0; j < 4; ++j) {
            int row = rbase + ty * 4 + j;
            if (row < N) {
                float d = sdis[tile * 64 + ty * 4 + j];
                __half2 h0 = __floats2half2_rn(acc[j].x * d, acc[j].y * d);
                __half2 h1 = __floats2half2_rn(acc[j].z * d, acc[j].w * d);
                ((uint2*)(hsb + (size_t)row * C))[tx] = make_uint2(h2u(h0), h2u(h1));
            }
        }
        __syncthreads();   // before next tile overwrites Xl
    }
}

// ---- K3: bucket edges by dst (global offs; atomic-free) ----
__global__ void __launch_bounds__(256)
bucket_kernel(const int* __restrict__ src, const int* __restrict__ dst,
              const unsigned* __restrict__ offs,
              const unsigned* __restrict__ part,
              const unsigned* __restrict__ rank, unsigned* __restrict__ ssrc, int E) {
    int g = blockIdx.x * 256 + threadIdx.x;
    int e0 = g * 4;
    if (e0 >= E) return;
    if (e0 + 4 <= E) {
        uint4 d4 = ((const uint4*)dst)[g];
        uint4 s4 = ((const uint4*)src)[g];
        uint4 r4 = ((const uint4*)rank)[g];
        #define PLACE(dd, ss, uu) { \
            unsigned xx = (uu) >> 26; \
            unsigned pos = offs[dd] + part[(size_t)(dd) * GRP + xx] + ((uu) & RMASK); \
            ssrc[pos] = (ss); }
        PLACE(d4.x, s4.x, r4.x);
        PLACE(d4.y, s4.y, r4.y);
        PLACE(d4.z, s4.z, r4.z);
        PLACE(d4.w, s4.w, r4.w);
        #undef PLACE
    } else {
        for (int e = e0; e < E; ++e) {
            unsigned dd = (unsigned)dst[e];
            unsigned uu = rank[e];
            unsigned xx = uu >> 26;
            unsigned pos = offs[dd] + part[(size_t)dd * GRP + xx] + (uu & RMASK);
            ssrc[pos] = (unsigned)src[e];
        }
    }
}

// ---- K4: gather; one wave/node; fp16 rows, packed-half2 accumulation ----
__global__ void gather_kernel(const unsigned* __restrict__ offs,
                              const unsigned* __restrict__ deg, const unsigned* __restrict__ ssrc,
                              const float* __restrict__ dis, const unsigned short* __restrict__ hsb,
                              const float* __restrict__ b, float* __restrict__ out, int n) {
    int node = blockIdx.x * 4 + (threadIdx.x >> 6);
    if (node >= n) return;
    int lane = threadIdx.x & 63;
    int g = lane >> 3;          // edge group 0..7
    int l = lane & 7;           // uint4 slot within 128B row (channels 8l..8l+7)

    // hoisted independent loads (fill the memory pipe early)
    uint4 u = make_uint4(0u, 0u, 0u, 0u);
    float4 bv = make_float4(0.f, 0.f, 0.f, 0.f);
    float di = 0.f;
    if (g < 2) {
        u  = ((const uint4*)(hsb + (size_t)node * C))[l];
        bv = ((const float4*)b)[l * 2 + g];
        di = dis[node];
    }

    unsigned off = offs[node];
    unsigned dg  = deg[node];
    __half2 a0 = u2h(0u), a1 = u2h(0u), a2 = u2h(0u), a3 = u2h(0u);
    if (dg) {
        // one coalesced round for the first 16 indices; groups pull via shfl
        unsigned l15 = (unsigned)lane & 15u;
        unsigned cl  = (l15 < dg) ? l15 : dg - 1u;
        unsigned idxv = ssrc[off + cl];
        #pragma unroll
        for (int r = 0; r < 2; ++r) {
            unsigned k = (unsigned)(r * 8) + (unsigned)g;
            unsigned sK = (unsigned)__shfl((int)idxv, (int)k);
            if (k < dg) {
                uint4 v = ((const uint4*)(hsb + (size_t)sK * C))[l];
                a0 = __hadd2(a0, u2h(v.x));
                a1 = __hadd2(a1, u2h(v.y));
                a2 = __hadd2(a2, u2h(v.z));
                a3 = __hadd2(a3, u2h(v.w));
            }
        }
        // rare heavy nodes (deg > 16)
        unsigned k = 16;
        for (; k + 8 <= dg; k += 8) {
            unsigned s0 = ssrc[off + k + g];
            uint4 v = ((const uint4*)(hsb + (size_t)s0 * C))[l];
            a0 = __hadd2(a0, u2h(v.x));
            a1 = __hadd2(a1, u2h(v.y));
            a2 = __hadd2(a2, u2h(v.z));
            a3 = __hadd2(a3, u2h(v.w));
        }
        if (k + g < dg) {
            unsigned s0 = ssrc[off + k + g];
            uint4 v = ((const uint4*)(hsb + (size_t)s0 * C))[l];
            a0 = __hadd2(a0, u2h(v.x));
            a1 = __hadd2(a1, u2h(v.y));
            a2 = __hadd2(a2, u2h(v.z));
            a3 = __hadd2(a3, u2h(v.w));
        }
    }
    // reduce across the 8 edge groups (xor 8, 16, 32) in packed fp16
    #pragma unroll
    for (int m = 8; m <= 32; m <<= 1) {
        a0 = __hadd2(a0, u2h((unsigned)__shfl_xor((int)h2u(a0), m)));
        a1 = __hadd2(a1, u2h((unsigned)__shfl_xor((int)h2u(a1), m)));
        a2 = __hadd2(a2, u2h((unsigned)__shfl_xor((int)h2u(a2), m)));
        a3 = __hadd2(a3, u2h((unsigned)__shfl_xor((int)h2u(a3), m)));
    }
    // groups 0/1 write the two float4 halves of the row
    if (g < 2) {
        unsigned w0 = (g == 0) ? u.x : u.z;
        unsigned w1 = (g == 0) ? u.y : u.w;
        float s0 = __low2float(u2h(w0)), s1 = __high2float(u2h(w0));
        float s2 = __low2float(u2h(w1)), s3 = __high2float(u2h(w1));
        __half2 ea = (g == 0) ? a0 : a2;
        __half2 eb = (g == 0) ? a1 : a3;
        float e0 = __low2float(ea), e1 = __high2float(ea);
        float e2 = __low2float(eb), e3 = __high2float(eb);
        float4 o;
        o.x = di * (s0 + e0) + bv.x;
        o.y = di * (s1 + e1) + bv.y;
        o.z = di * (s2 + e2) + bv.z;
        o.w = di * (s3 + e3) + bv.w;
        ((float4*)(out + (size_t)node * C))[l * 2 + g] = o;
    }
}

extern "C" void kernel_launch(void* const* d_in, const int* in_sizes, int n_in,
                              void* d_out, int out_size, void* d_ws, size_t ws_size,
                              hipStream_t stream) {
    const float* x   = (const float*)d_in[0];
    const int*   ei  = (const int*)d_in[1];   // [2, E]: src = ei[e], dst = ei[E+e]
    const float* W   = (const float*)d_in[2];
    const float* b   = (const float*)d_in[3];
    float*       out = (float*)d_out;

    const int N = in_sizes[0] / C;
    const int E = in_sizes[1] / 2;
    const int* src = ei;
    const int* dst = ei + E;

    // count-kernel geometry: RNG ranges of R bins (R <= 6400), GRP edge groups
    int RNG = 16;
    while ((N + RNG - 1) / RNG > 6400) RNG *= 2;   // N=100k -> RNG=16, R=6250
    const int R   = (N + RNG - 1) / RNG;
    const int Ec  = (((E + GRP - 1) / GRP) + 3) & ~3;   // group chunk, 16B-aligned
    const int nch = (N + 255) >> 8;           // scan/gemm chunks of 256 nodes
    const int Npad = RNG * R;                 // padded node count for part rows

    // workspace layout (256B aligned slots)
    char* ws = (char*)d_ws;
    size_t o = 0;
    auto carve = [&](size_t bytes) { char* p = ws + o; o = (o + bytes + 255) & ~(size_t)255; return p; };
    unsigned* part      = (unsigned*)carve((size_t)Npad * GRP * 4);   // node-major [node][GRP]
    unsigned* deg       = (unsigned*)carve((size_t)N * 4);
    unsigned* offs      = (unsigned*)carve((size_t)N * 4);
    unsigned* gctr      = (unsigned*)carve(256);
    float*    dis       = (float*)carve((size_t)N * 4);
    unsigned* rank      = (unsigned*)carve((size_t)E * 4);
    unsigned* ssrc      = (unsigned*)carve((size_t)E * 4);
    unsigned short* hsb = (unsigned short*)carve((size_t)N * C * 2);

    // K1: LDS-histogram count (no zero pass needed; also resets gctr)
    count_range_kernel<<<GRP * RNG, 256, 0, stream>>>(dst, part, R, RNG, rank, gctr, Ec, E);

    // K2: fused chunk-scan + gemm (global offs via gctr)
    scan_gemm_kernel<<<nch, 256, 0, stream>>>(part, x, W, deg, offs, gctr, dis, hsb, N);

    // K3: bucket
    int ng4 = (E + 3) / 4;
    bucket_kernel<<<(ng4 + 255) / 256, 256, 0, stream>>>(src, dst, offs, part, rank, ssrc, E);

    // K4: gather + self loop + bias
    gather_kernel<<<(N + 3) / 4, 256, 0, stream>>>(offs, deg, ssrc, dis, hsb, b, out, N);
}

// Round 22
// 117.441 us; speedup vs baseline: 1.2659x; 1.2659x over previous
//
#include <hip/hip_runtime.h>
#include <hip/hip_bf16.h>
#include <hip/hip_fp16.h>

#define C 64
#define GRP 32         // edge groups; tag bits 27..31 (g<32), rank in bits 0..26

__device__ __forceinline__ __half2 u2h(unsigned u) {
    __half2 h; *(unsigned*)&h = u; return h;
}
__device__ __forceinline__ unsigned h2u(__half2 h) {
    return *(unsigned*)&h;
}

// ---- K1: LDS-histogram count (R18 geometry; gctr removed) ----
// GRP=32/RNG=32: 1024 blocks (4/CU), 30 uint4 loads/thread; group-major part
// dump is block-contiguous. LDS atomics replace the 41us global atomic wall.
// R21 post-mortem: the old gctr (plain-store reset + cross-kernel atomic RMW)
// raced intermittently under graph replay AND made chunk bases arrival-ordered
// (different work per replay, violating the determinism contract). Removed.
__global__ void __launch_bounds__(256)
count_range_kernel(const int* __restrict__ dst, unsigned* __restrict__ part, int S, int R,
                   int RNG, unsigned* __restrict__ rank, int Ec, int E) {
    __shared__ unsigned hist[4096];        // supports R <= 4096
    int t = threadIdx.x;
    int g = blockIdx.x / RNG;
    int r = blockIdx.x - g * RNG;
    unsigned rbase = (unsigned)r * (unsigned)R;
    for (int i = t; i < R; i += 256) hist[i] = 0u;
    __syncthreads();

    int e0 = g * Ec;                       // Ec is a multiple of 4; e0 16B-aligned
    int e1 = min(E, e0 + Ec);
    int nv = (e1 - e0) >> 2;
    const uint4* dv = (const uint4*)(dst + e0);
    unsigned gtag = (unsigned)g << 27;
    for (int i = t; i < nv; i += 256) {
        uint4 d4 = dv[i];
        int eb = e0 + i * 4;
        unsigned o0 = d4.x - rbase, o1 = d4.y - rbase, o2 = d4.z - rbase, o3 = d4.w - rbase;
        if (o0 < (unsigned)R) rank[eb + 0] = gtag | atomicAdd(&hist[o0], 1u);
        if (o1 < (unsigned)R) rank[eb + 1] = gtag | atomicAdd(&hist[o1], 1u);
        if (o2 < (unsigned)R) rank[eb + 2] = gtag | atomicAdd(&hist[o2], 1u);
        if (o3 < (unsigned)R) rank[eb + 3] = gtag | atomicAdd(&hist[o3], 1u);
    }
    for (int e = e0 + nv * 4 + t; e < e1; e += 256) {   // scalar tail
        unsigned o = (unsigned)dst[e] - rbase;
        if (o < (unsigned)R) rank[e] = gtag | atomicAdd(&hist[o], 1u);
    }
    __syncthreads();
    unsigned* prow = part + (size_t)g * S + rbase;
    for (int i = t; i < R; i += 256) prow[i] = hist[i];
}

// ---- K2: fused per-chunk scan + gemm (chunk = 256 nodes, 4 tiles of 64 rows) ----
// offs is CHUNK-LOCAL; bsum[c] = chunk sum. Deterministic (no atomics).
__global__ void __launch_bounds__(256, 4)
scan_gemm_kernel(unsigned* __restrict__ part, int S,
                 const float* __restrict__ x, const float* __restrict__ W,
                 unsigned* __restrict__ deg, unsigned* __restrict__ offs,
                 unsigned* __restrict__ bsum, float* __restrict__ dis,
                 unsigned short* __restrict__ hsb, int N) {
    __shared__ float Wl[64][64];
    __shared__ float Xl[64][68];
    __shared__ unsigned s[256];
    __shared__ float sdis[256];
    int t = threadIdx.x;
    int nbase = blockIdx.x * 256;

    for (int i = t; i < 1024; i += 256) {
        ((float4*)Wl)[i] = ((const float4*)W)[i];
    }

    // --- phase A: one node per thread ---
    int i = nbase + t;
    unsigned degv = 0;
    if (i < N) {
        unsigned run = 0;
        #pragma unroll
        for (int xx = 0; xx < GRP; ++xx) {
            unsigned* p = &part[(size_t)xx * S + i];
            unsigned v = *p;
            *p = run;                 // exclusive prefix across groups
            run += v;
        }
        degv = run;
        deg[i] = run;
        float dv = rsqrtf((float)(run + 1u));
        dis[i] = dv;
        sdis[t] = dv;
    } else {
        sdis[t] = 0.f;
    }
    s[t] = degv;
    __syncthreads();
    for (int d = 1; d < 256; d <<= 1) {
        unsigned v = (t >= d) ? s[t - d] : 0u;
        __syncthreads();
        s[t] += v;
        __syncthreads();
    }
    if (t == 255) bsum[blockIdx.x] = s[255];   // chunk sum (prefix-scanned by K3)
    if (i < N) offs[i] = s[t] - degv;          // chunk-local exclusive offset
    __syncthreads();

    // --- phase B: 4 gemm tiles of 64 rows ---
    int tx = t & 15;      // channel group
    int ty = t >> 4;      // row group
    for (int tile = 0; tile < 4; ++tile) {
        int rbase = nbase + tile * 64;
        if (rbase >= N) break;            // block-uniform
        for (int ii = t; ii < 1024; ii += 256) {
            int r = ii >> 4, kq = ii & 15;
            float4 v;
            if (rbase + r < N) v = ((const float4*)(x + (size_t)(rbase + r) * C))[kq];
            else               v = make_float4(0.f, 0.f, 0.f, 0.f);
            *(float4*)&Xl[r][kq * 4] = v;
        }
        __syncthreads();
        float4 acc[4];
        #pragma unroll
        for (int j = 0; j < 4; ++j) acc[j] = make_float4(0.f, 0.f, 0.f, 0.f);
        #pragma unroll 2
        for (int kb = 0; kb < 16; ++kb) {
            float4 wv0 = *(const float4*)&Wl[kb * 4 + 0][tx * 4];
            float4 wv1 = *(const float4*)&Wl[kb * 4 + 1][tx * 4];
            float4 wv2 = *(const float4*)&Wl[kb * 4 + 2][tx * 4];
            float4 wv3 = *(const float4*)&Wl[kb * 4 + 3][tx * 4];
            #pragma unroll
            for (int j = 0; j < 4; ++j) {
                float4 xv = *(const float4*)&Xl[ty * 4 + j][kb * 4];
                acc[j].x = fmaf(xv.x, wv0.x, acc[j].x);
                acc[j].y = fmaf(xv.x, wv0.y, acc[j].y);
                acc[j].z = fmaf(xv.x, wv0.z, acc[j].z);
                acc[j].w = fmaf(xv.x, wv0.w, acc[j].w);
                acc[j].x = fmaf(xv.y, wv1.x, acc[j].x);
                acc[j].y = fmaf(xv.y, wv1.y, acc[j].y);
                acc[j].z = fmaf(xv.y, wv1.z, acc[j].z);
                acc[j].w = fmaf(xv.y, wv1.w, acc[j].w);
                acc[j].x = fmaf(xv.z, wv2.x, acc[j].x);
                acc[j].y = fmaf(xv.z, wv2.y, acc[j].y);
                acc[j].z = fmaf(xv.z, wv2.z, acc[j].z);
                acc[j].w = fmaf(xv.z, wv2.w, acc[j].w);
                acc[j].x = fmaf(xv.w, wv3.x, acc[j].x);
                acc[j].y = fmaf(xv.w, wv3.y, acc[j].y);
                acc[j].z = fmaf(xv.w, wv3.z, acc[j].z);
                acc[j].w = fmaf(xv.w, wv3.w, acc[j].w);
            }
        }
        #pragma unroll
        for (int j = 0; j < 4; ++j) {
            int row = rbase + ty * 4 + j;
            if (row < N) {
                float d = sdis[tile * 64 + ty * 4 + j];
                __half2 h0 = __floats2half2_rn(acc[j].x * d, acc[j].y * d);
                __half2 h1 = __floats2half2_rn(acc[j].z * d, acc[j].w * d);
                ((uint2*)(hsb + (size_t)row * C))[tx] = make_uint2(h2u(h0), h2u(h1));
            }
        }
        __syncthreads();   // before next tile overwrites Xl
    }
}

// ---- K3: exclusive prefix of bsum (single block; nb <= 512) ----
__global__ void scan2_kernel(unsigned* __restrict__ bsum, int nb) {
    __shared__ unsigned s[512];
    int t = threadIdx.x;
    s[t]       = (t < nb)       ? bsum[t]       : 0u;
    s[t + 256] = (t + 256 < nb) ? bsum[t + 256] : 0u;
    __syncthreads();
    for (int d = 1; d < 512; d <<= 1) {
        unsigned v0 = (t >= d) ? s[t - d] : 0u;
        unsigned v1 = s[t + 256 - d];
        __syncthreads();
        s[t]       += v0;
        s[t + 256] += v1;
        __syncthreads();
    }
    if (t < nb)       bsum[t]       = (t == 0) ? 0u : s[t - 1];
    if (t + 256 < nb) bsum[t + 256] = s[t + 255];
}

// ---- K4: bucket edges by dst (chunk-local offs + prefix bsum; atomic-free) ----
__global__ void __launch_bounds__(256)
bucket_kernel(const int* __restrict__ src, const int* __restrict__ dst,
              const unsigned* __restrict__ offs, const unsigned* __restrict__ bsum,
              const unsigned* __restrict__ part, int S,
              const unsigned* __restrict__ rank, unsigned* __restrict__ ssrc, int E) {
    int g = blockIdx.x * 256 + threadIdx.x;
    int e0 = g * 4;
    if (e0 >= E) return;
    if (e0 + 4 <= E) {
        uint4 d4 = ((const uint4*)dst)[g];
        uint4 s4 = ((const uint4*)src)[g];
        uint4 r4 = ((const uint4*)rank)[g];
        #define PLACE(dd, ss, uu) { \
            unsigned xx = (uu) >> 27; \
            unsigned pos = offs[dd] + bsum[(dd) >> 8] + part[(size_t)xx * S + (dd)] + ((uu) & 0x07FFFFFFu); \
            ssrc[pos] = (ss); }
        PLACE(d4.x, s4.x, r4.x);
        PLACE(d4.y, s4.y, r4.y);
        PLACE(d4.z, s4.z, r4.z);
        PLACE(d4.w, s4.w, r4.w);
        #undef PLACE
    } else {
        for (int e = e0; e < E; ++e) {
            unsigned dd = (unsigned)dst[e];
            unsigned uu = rank[e];
            unsigned xx = uu >> 27;
            unsigned pos = offs[dd] + bsum[dd >> 8] + part[(size_t)xx * S + dd] + (uu & 0x07FFFFFFu);
            ssrc[pos] = (unsigned)src[e];
        }
    }
}

// ---- K5: gather; one wave/node; fp16 rows, packed-half2 accumulation ----
__global__ void gather_kernel(const unsigned* __restrict__ offs, const unsigned* __restrict__ bsum,
                              const unsigned* __restrict__ deg, const unsigned* __restrict__ ssrc,
                              const float* __restrict__ dis, const unsigned short* __restrict__ hsb,
                              const float* __restrict__ b, float* __restrict__ out, int n) {
    int node = blockIdx.x * 4 + (threadIdx.x >> 6);
    if (node >= n) return;
    int lane = threadIdx.x & 63;
    int g = lane >> 3;          // edge group 0..7
    int l = lane & 7;           // uint4 slot within 128B row (channels 8l..8l+7)

    // hoisted independent loads (fill the memory pipe early)
    uint4 u = make_uint4(0u, 0u, 0u, 0u);
    float4 bv = make_float4(0.f, 0.f, 0.f, 0.f);
    float di = 0.f;
    if (g < 2) {
        u  = ((const uint4*)(hsb + (size_t)node * C))[l];
        bv = ((const float4*)b)[l * 2 + g];
        di = dis[node];
    }

    unsigned off = offs[node] + bsum[node >> 8];
    unsigned dg  = deg[node];
    __half2 a0 = u2h(0u), a1 = u2h(0u), a2 = u2h(0u), a3 = u2h(0u);
    if (dg) {
        // one coalesced round for the first 16 indices; groups pull via shfl
        unsigned l15 = (unsigned)lane & 15u;
        unsigned cl  = (l15 < dg) ? l15 : dg - 1u;
        unsigned idxv = ssrc[off + cl];
        #pragma unroll
        for (int r = 0; r < 2; ++r) {
            unsigned k = (unsigned)(r * 8) + (unsigned)g;
            unsigned sK = (unsigned)__shfl((int)idxv, (int)k);
            if (k < dg) {
                uint4 v = ((const uint4*)(hsb + (size_t)sK * C))[l];
                a0 = __hadd2(a0, u2h(v.x));
                a1 = __hadd2(a1, u2h(v.y));
                a2 = __hadd2(a2, u2h(v.z));
                a3 = __hadd2(a3, u2h(v.w));
            }
        }
        // rare heavy nodes (deg > 16)
        unsigned k = 16;
        for (; k + 8 <= dg; k += 8) {
            unsigned s0 = ssrc[off + k + g];
            uint4 v = ((const uint4*)(hsb + (size_t)s0 * C))[l];
            a0 = __hadd2(a0, u2h(v.x));
            a1 = __hadd2(a1, u2h(v.y));
            a2 = __hadd2(a2, u2h(v.z));
            a3 = __hadd2(a3, u2h(v.w));
        }
        if (k + g < dg) {
            unsigned s0 = ssrc[off + k + g];
            uint4 v = ((const uint4*)(hsb + (size_t)s0 * C))[l];
            a0 = __hadd2(a0, u2h(v.x));
            a1 = __hadd2(a1, u2h(v.y));
            a2 = __hadd2(a2, u2h(v.z));
            a3 = __hadd2(a3, u2h(v.w));
        }
    }
    // reduce across the 8 edge groups (xor 8, 16, 32) in packed fp16
    #pragma unroll
    for (int m = 8; m <= 32; m <<= 1) {
        a0 = __hadd2(a0, u2h((unsigned)__shfl_xor((int)h2u(a0), m)));
        a1 = __hadd2(a1, u2h((unsigned)__shfl_xor((int)h2u(a1), m)));
        a2 = __hadd2(a2, u2h((unsigned)__shfl_xor((int)h2u(a2), m)));
        a3 = __hadd2(a3, u2h((unsigned)__shfl_xor((int)h2u(a3), m)));
    }
    // groups 0/1 write the two float4 halves of the row
    if (g < 2) {
        unsigned w0 = (g == 0) ? u.x : u.z;
        unsigned w1 = (g == 0) ? u.y : u.w;
        float s0 = __low2float(u2h(w0)), s1 = __high2float(u2h(w0));
        float s2 = __low2float(u2h(w1)), s3 = __high2float(u2h(w1));
        __half2 ea = (g == 0) ? a0 : a2;
        __half2 eb = (g == 0) ? a1 : a3;
        float e0 = __low2float(ea), e1 = __high2float(ea);
        float e2 = __low2float(eb), e3 = __high2float(eb);
        float4 o;
        o.x = di * (s0 + e0) + bv.x;
        o.y = di * (s1 + e1) + bv.y;
        o.z = di * (s2 + e2) + bv.z;
        o.w = di * (s3 + e3) + bv.w;
        ((float4*)(out + (size_t)node * C))[l * 2 + g] = o;
    }
}

extern "C" void kernel_launch(void* const* d_in, const int* in_sizes, int n_in,
                              void* d_out, int out_size, void* d_ws, size_t ws_size,
                              hipStream_t stream) {
    const float* x   = (const float*)d_in[0];
    const int*   ei  = (const int*)d_in[1];   // [2, E]: src = ei[e], dst = ei[E+e]
    const float* W   = (const float*)d_in[2];
    const float* b   = (const float*)d_in[3];
    float*       out = (float*)d_out;

    const int N = in_sizes[0] / C;
    const int E = in_sizes[1] / 2;
    const int* src = ei;
    const int* dst = ei + E;

    // count-kernel geometry: RNG ranges of R bins (R <= 4096), GRP edge groups
    int RNG = (N + 4095) / 4096;
    if (RNG < 32) RNG = 32;
    const int R   = (N + RNG - 1) / RNG;
    const int S   = (RNG * R + 63) & ~63;     // partial-histogram stride (covers RNG*R)
    const int Ec  = (((E + GRP - 1) / GRP) + 3) & ~3;   // group chunk, 16B-aligned
    const int nch = (N + 255) >> 8;           // scan/gemm chunks of 256 nodes (<=512)

    // workspace layout (256B aligned slots)
    char* ws = (char*)d_ws;
    size_t o = 0;
    auto carve = [&](size_t bytes) { char* p = ws + o; o = (o + bytes + 255) & ~(size_t)255; return p; };
    unsigned* part      = (unsigned*)carve((size_t)GRP * S * 4);
    unsigned* deg       = (unsigned*)carve((size_t)N * 4);
    unsigned* offs      = (unsigned*)carve((size_t)N * 4);
    unsigned* bsum      = (unsigned*)carve(1024 * 4);
    float*    dis       = (float*)carve((size_t)N * 4);
    unsigned* rank      = (unsigned*)carve((size_t)E * 4);
    unsigned* ssrc      = (unsigned*)carve((size_t)E * 4);
    unsigned short* hsb = (unsigned short*)carve((size_t)N * C * 2);

    // K1: LDS-histogram count (no zero pass needed)
    count_range_kernel<<<GRP * RNG, 256, 0, stream>>>(dst, part, S, R, RNG, rank, Ec, E);

    // K2: fused chunk-scan + gemm (chunk-local offs + bsum)
    scan_gemm_kernel<<<nch, 256, 0, stream>>>(part, S, x, W, deg, offs, bsum, dis, hsb, N);

    // K3: exclusive prefix of bsum (deterministic chunk bases)
    scan2_kernel<<<1, 256, 0, stream>>>(bsum, nch);

    // K4: bucket
    int ng4 = (E + 3) / 4;
    bucket_kernel<<<(ng4 + 255) / 256, 256, 0, stream>>>(src, dst, offs, bsum, part, S, rank, ssrc, E);

    // K5: gather + self loop + bias
    gather_kernel<<<(N + 3) / 4, 256, 0, stream>>>(offs, bsum, deg, ssrc, dis, hsb, b, out, N);
}